// Round 5
// baseline (167.505 us; speedup 1.0000x reference)
//
#include <hip/hip_runtime.h>

#define BB 64
#define CC 64
#define TT 4000

// ---- gram (MFMA) geometry ----
#define SLABS 16
#define TSLAB 250            // staged padded to 256 t (32 chunks of 8 bf16)
#define GP_PITCH 264         // shorts per LDS row (16B-aligned rows, chunk 32 = pad)

// ---- apply geometry ----
#define TPB 128
#define NT2 ((TT + TPB - 1) / TPB)   // 32
#define XTP 72               // shorts per xt row (16 chunks of 4 used + 2 pad)
#define APITCH 72            // shorts per al row

// ws layout (floats): G_part[16][64][64][64] | S_part[16][64][64] | attG[64][64][64]
#define GPART_ELEMS ((size_t)SLABS * BB * CC * CC)
#define SPART_ELEMS ((size_t)SLABS * BB * CC)

typedef short short8 __attribute__((ext_vector_type(8)));
typedef float f32x16 __attribute__((ext_vector_type(16)));

__device__ __forceinline__ short f2bf(float f) {
    unsigned u = __float_as_uint(f);
    u = (u + 0x7FFFu + ((u >> 16) & 1u)) >> 16;   // round-to-nearest-even
    return (short)u;
}
__device__ __forceinline__ float bfpair(unsigned u) {   // sum of 2 packed bf16
    return __uint_as_float(u << 16) + __uint_as_float(u & 0xFFFF0000u);
}

// ---------------- gram (unchanged from R4, passing) ----------------
__global__ __launch_bounds__(256)
void gram_mfma(const float* __restrict__ x, float* __restrict__ G_part,
               float* __restrict__ S_part) {
    __shared__ short xs[CC * GP_PITCH];
    __shared__ float sred[4 * 64];
    const int b    = blockIdx.x / SLABS;
    const int slab = blockIdx.x % SLABS;
    const int t0   = slab * TSLAB;
    const int tid  = threadIdx.x;
    const int lane = tid & 63;
    const int wave = tid >> 6;
    const float* xb = x + (size_t)b * CC * TT;

    for (int i = tid; i < 64 * 64; i += 256) {
        int row = i >> 6, tq = i & 63;
        float4 v = make_float4(0.f, 0.f, 0.f, 0.f);
        if (tq < 62) {
            v = *(const float4*)(xb + row * TT + t0 + 4 * tq);
        } else if (tq == 62) {
            const float* p = xb + row * TT + t0 + 248;
            v.x = p[0]; v.y = p[1];
        }
        short4 sv;
        sv.x = f2bf(v.x); sv.y = f2bf(v.y); sv.z = f2bf(v.z); sv.w = f2bf(v.w);
        int pc = (tq >> 1) ^ (row & 7);
        *(short4*)(xs + row * GP_PITCH + pc * 8 + (tq & 1) * 4) = sv;
    }
    __syncthreads();

    {
        const short* rowp = xs + lane * GP_PITCH;
        float s = 0.f;
        #pragma unroll
        for (int j = 0; j < 8; ++j) {
            int pc = (wave * 8 + j) ^ (lane & 7);
            uint2 u0 = *(const uint2*)(rowp + pc * 8);
            uint2 u1 = *(const uint2*)(rowp + pc * 8 + 4);
            s += bfpair(u0.x) + bfpair(u0.y) + bfpair(u1.x) + bfpair(u1.y);
        }
        sred[wave * 64 + lane] = s;
    }
    __syncthreads();
    if (tid < 64) {
        float s = sred[tid] + sred[64 + tid] + sred[128 + tid] + sred[192 + tid];
        S_part[(slab * BB + b) * CC + tid] = s;
    }

    const int r0 = (wave >> 1) * 32, c0 = (wave & 1) * 32;
    const int m = lane & 31, half = lane >> 5;
    f32x16 acc;
    #pragma unroll
    for (int z = 0; z < 16; ++z) acc[z] = 0.f;
    #pragma unroll
    for (int ks = 0; ks < 16; ++ks) {
        const int ck = ks * 2 + half;
        short8 av = *(const short8*)(xs + (r0 + m) * GP_PITCH + (ck ^ (m & 7)) * 8);
        short8 bv = *(const short8*)(xs + (c0 + m) * GP_PITCH + (ck ^ (m & 7)) * 8);
        acc = __builtin_amdgcn_mfma_f32_32x32x16_bf16(av, bv, acc, 0, 0, 0);
    }
    float* gp = G_part + ((size_t)slab * BB + b) * (CC * CC);
    #pragma unroll
    for (int r = 0; r < 16; ++r) {
        const int row = (r & 3) + 8 * (r >> 2) + 4 * half;
        gp[(r0 + row) * CC + (c0 + m)] = acc[r];
    }
}

// ---------------- softmax: 512 blocks, one wave per attention row ----------------
// block = (b, g): rows r = 8g..8g+7 of attention. attG[b][c][e] = P[e][c].
__global__ __launch_bounds__(256)
void softmax_split(const float* __restrict__ w1, const float* __restrict__ b1,
                   const float* __restrict__ w2, const float* __restrict__ b2,
                   const float* __restrict__ G_part, const float* __restrict__ S_part,
                   float* __restrict__ attG) {
    __shared__ float Sb[64];
    __shared__ float Pt[64 * 12];        // Pt[c][r_loc], pitch 12
    const int b = blockIdx.x >> 3, g = blockIdx.x & 7;
    const int tid = threadIdx.x;
    const int lane = tid & 63, w = tid >> 6;

    if (tid < 64) {
        float s = 0.f;
        #pragma unroll
        for (int sl = 0; sl < SLABS; ++sl)
            s += S_part[(sl * BB + b) * CC + tid];
        Sb[tid] = s;
    }
    float A = 0.f, Bc = 0.f, Be = 0.f, Cc = 0.f;
    #pragma unroll
    for (int j = 0; j < 8; ++j) {
        float a1 = w1[j], a2 = w2[j], q1 = b1[j], q2 = b2[j];
        A += a1 * a2; Bc += a1 * q2; Be += q1 * a2; Cc += q1 * q2;
    }
    Cc *= (float)TT;
    __syncthreads();

    #pragma unroll
    for (int pass = 0; pass < 2; ++pass) {
        const int rl = 4 * pass + w;          // row_local in [0,8)
        const int r  = 8 * g + rl;
        float v = 0.f;
        #pragma unroll
        for (int sl = 0; sl < SLABS; ++sl)
            v += G_part[(((size_t)sl * BB + b) << 12) + r * 64 + lane];
        float en = A * v + Bc * Sb[r] + Be * Sb[lane] + Cc;
        float mx = en, mn = en;
        #pragma unroll
        for (int off = 32; off; off >>= 1) {
            mx = fmaxf(mx, __shfl_xor(mx, off, 64));
            mn = fminf(mn, __shfl_xor(mn, off, 64));
        }
        float p = __expf((en - mn) / (mx - mn + 1e-8f));
        float sum = p;
        #pragma unroll
        for (int off = 32; off; off >>= 1) sum += __shfl_xor(sum, off, 64);
        Pt[lane * 12 + rl] = p / sum;         // Pt[c=lane][rl] = att[r][c]
    }
    __syncthreads();
    float* ab = attG + (size_t)b * 4096;
    if (tid < 128) {
        int c = tid >> 1, h = tid & 1;
        float4 v = *(const float4*)(Pt + c * 12 + 4 * h);
        *(float4*)(ab + c * 64 + 8 * g + 4 * h) = v;   // attG[c][8g+4h .. +3]
    }
}

// ---------------- apply: bf16 MFMA with vectorized B-fragments ----------------
// out[b,c,t] = gamma * sum_e att[e][c]*x[e][t] + x[b,c,t]
// A = attG rows (al[c][e]); B from transposed bf16 tile xt[t][e] (chunk-XOR swizzled)
__global__ __launch_bounds__(256)
void apply_mfma(const float* __restrict__ x, const float* __restrict__ attG,
                const float* __restrict__ gamma, float* __restrict__ out) {
    __shared__ short xt[TPB * XTP];      // 18.4 KB bf16, xt[t][e] swizzled
    __shared__ short al[CC * APITCH];    // 9.2 KB  bf16, al[c][e]
    const int b  = blockIdx.x / NT2;
    const int t0 = (blockIdx.x % NT2) * TPB;
    const int tid = threadIdx.x;
    const int lane = tid & 63, wave = tid >> 6;
    const float* xb = x + (size_t)b * CC * TT;
    const float* ab = attG + (size_t)b * CC * CC;

    // stage attention -> bf16
    for (int i = tid; i < CC * CC / 4; i += 256) {
        int c = i >> 4, q = i & 15;
        float4 v = *(const float4*)(ab + c * CC + 4 * q);
        short4 sv;
        sv.x = f2bf(v.x); sv.y = f2bf(v.y); sv.z = f2bf(v.z); sv.w = f2bf(v.w);
        *(short4*)(al + c * APITCH + 4 * q) = sv;
    }
    // stage x -> transposed bf16 tile. thread: (tg = tid&31 -> 4 t, eg -> 4 e)
    #pragma unroll
    for (int it = 0; it < 2; ++it) {
        const int tg = tid & 31;
        const int eg = (tid >> 5) + 8 * it;       // [0,16)
        const int e0 = 4 * eg;
        const int tl = 4 * tg;
        const int t  = t0 + tl;
        float4 v0, v1, v2, v3;
        if (t < TT) {
            v0 = *(const float4*)(xb + (e0 + 0) * TT + t);
            v1 = *(const float4*)(xb + (e0 + 1) * TT + t);
            v2 = *(const float4*)(xb + (e0 + 2) * TT + t);
            v3 = *(const float4*)(xb + (e0 + 3) * TT + t);
        } else {
            v0 = v1 = v2 = v3 = make_float4(0.f, 0.f, 0.f, 0.f);
        }
        #pragma unroll
        for (int j = 0; j < 4; ++j) {
            float a = (j == 0) ? v0.x : (j == 1) ? v0.y : (j == 2) ? v0.z : v0.w;
            float bq = (j == 0) ? v1.x : (j == 1) ? v1.y : (j == 2) ? v1.z : v1.w;
            float cq = (j == 0) ? v2.x : (j == 1) ? v2.y : (j == 2) ? v2.z : v2.w;
            float dq = (j == 0) ? v3.x : (j == 1) ? v3.y : (j == 2) ? v3.z : v3.w;
            short4 sv; sv.x = f2bf(a); sv.y = f2bf(bq); sv.z = f2bf(cq); sv.w = f2bf(dq);
            int pc = eg ^ ((tl + j) & 15);        // chunk-XOR swizzle
            *(short4*)(xt + (tl + j) * XTP + 4 * pc) = sv;
        }
    }
    __syncthreads();

    const int m = lane & 31, half = lane >> 5;
    const int c0 = (wave & 1) * 32;
    const int tb = (wave >> 1) * 64;
    const int s0 = (tb + m) & 15;                  // same for tb and tb+32
    f32x16 acc0, acc1;
    #pragma unroll
    for (int z = 0; z < 16; ++z) { acc0[z] = 0.f; acc1[z] = 0.f; }

    #pragma unroll
    for (int ks = 0; ks < 4; ++ks) {
        short8 av = *(const short8*)(al + (c0 + m) * APITCH + ks * 16 + 8 * half);
        const int lc = 4 * ks + 2 * half;          // even logical chunk
        const int p0 = lc ^ s0, p1 = p0 ^ 1;
        const short* r0p = xt + (tb + m) * XTP;
        const short* r1p = xt + (tb + 32 + m) * XTP;
        short4 b0l = *(const short4*)(r0p + 4 * p0);
        short4 b0h = *(const short4*)(r0p + 4 * p1);
        short4 b1l = *(const short4*)(r1p + 4 * p0);
        short4 b1h = *(const short4*)(r1p + 4 * p1);
        short8 bv0 = {b0l.x, b0l.y, b0l.z, b0l.w, b0h.x, b0h.y, b0h.z, b0h.w};
        short8 bv1 = {b1l.x, b1l.y, b1l.z, b1l.w, b1h.x, b1h.y, b1h.z, b1h.w};
        acc0 = __builtin_amdgcn_mfma_f32_32x32x16_bf16(av, bv0, acc0, 0, 0, 0);
        acc1 = __builtin_amdgcn_mfma_f32_32x32x16_bf16(av, bv1, acc1, 0, 0, 0);
    }

    const float gm = gamma[0];
    float* ob = out + (size_t)b * CC * TT;
    const int tg0 = t0 + tb + m, tg1 = tg0 + 32;
    #pragma unroll
    for (int r = 0; r < 16; ++r) {
        const int row = (r & 3) + 8 * (r >> 2) + 4 * half;
        const int c = c0 + row;
        if (tg0 < TT) ob[c * TT + tg0] = gm * acc0[r] + xb[c * TT + tg0];
        if (tg1 < TT) ob[c * TT + tg1] = gm * acc1[r] + xb[c * TT + tg1];
    }
}

extern "C" void kernel_launch(void* const* d_in, const int* in_sizes, int n_in,
                              void* d_out, int out_size, void* d_ws, size_t ws_size,
                              hipStream_t stream) {
    const float* x  = (const float*)d_in[0];
    const float* w1 = (const float*)d_in[1];
    const float* b1 = (const float*)d_in[2];
    const float* w2 = (const float*)d_in[3];
    const float* b2 = (const float*)d_in[4];
    const float* gm = (const float*)d_in[5];
    float* out = (float*)d_out;

    float* G_part = (float*)d_ws;
    float* S_part = G_part + GPART_ELEMS;
    float* attG   = S_part + SPART_ELEMS;

    hipLaunchKernelGGL(gram_mfma, dim3(BB * SLABS), dim3(256), 0, stream,
                       x, G_part, S_part);
    hipLaunchKernelGGL(softmax_split, dim3(BB * 8), dim3(256), 0, stream,
                       w1, b1, w2, b2, G_part, S_part, attG);
    hipLaunchKernelGGL(apply_mfma, dim3(BB * NT2), dim3(256), 0, stream,
                       x, attG, gm, out);
}